// Round 1
// baseline (400.773 us; speedup 1.0000x reference)
//
#include <hip/hip_runtime.h>

#define CDIM 768
#define SDIM 4096
#define SV (SDIM / 4) // row length in float4

typedef float nfloat4 __attribute__((ext_vector_type(4))); // native vec for nontemporal builtin

// out[b,c] = bias[c] + sum_k X[b,k] * W[c,k]   (one wave per output element)
__global__ __launch_bounds__(256) void small_gemm_kernel(
    const float* __restrict__ X, const float* __restrict__ W,
    const float* __restrict__ bias, float* __restrict__ out,
    int Cn, int K)
{
    int gid  = blockIdx.x * blockDim.x + threadIdx.x;
    int wid  = gid >> 6;
    int lane = threadIdx.x & 63;
    int total = 16 * Cn;
    if (wid >= total) return;
    int b = wid / Cn;
    int c = wid - b * Cn;
    const float* x = X + (size_t)b * K;
    const float* w = W + (size_t)c * K;
    float acc = 0.f;
    for (int k = lane * 4; k < K; k += 256) {
        float4 xv = *(const float4*)(x + k);
        float4 wv = *(const float4*)(w + k);
        acc += xv.x * wv.x + xv.y * wv.y + xv.z * wv.z + xv.w * wv.w;
    }
#pragma unroll
    for (int m = 32; m; m >>= 1) acc += __shfl_xor(acc, m, 64);
    if (lane == 0) out[wid] = acc + bias[c];
}

// Single-read fused add+LN.
// Block = 512 threads, tile = 32 s-positions (8 float4 columns) x all 768 c.
// Thread t: si = t&7 (one float4 s-column), cg = t>>3 (0..63), 12 c's per thread.
// x = sp + proj held in 12 float4 REGISTERS: stats pass and normalize pass both
// run from registers -> sp is read from HBM exactly once (was twice).
__global__ __launch_bounds__(512) void fused_add_ln_1pass(
    const float* __restrict__ sp, const float* __restrict__ proj,
    const float* __restrict__ gamma, const float* __restrict__ beta,
    float* __restrict__ out)
{
    __shared__ float s_proj[CDIM], s_gamma[CDIM], s_beta[CDIM];
    __shared__ float4 red_s[64][8];
    __shared__ float4 red_q[64][8];
    __shared__ float4 red2_s[8][8];
    __shared__ float4 red2_q[8][8];
    __shared__ float4 s_mu[8];
    __shared__ float4 s_rs[8];

    const int b  = blockIdx.y;
    const int s0 = blockIdx.x * 32;
    const int t  = threadIdx.x;
    for (int i = t; i < CDIM; i += 512) {
        s_proj[i]  = proj[b * CDIM + i];
        s_gamma[i] = gamma[i];
        s_beta[i]  = beta[i];
    }
    __syncthreads();

    const int si = t & 7;
    const int cg = t >> 3;
    const int c0 = cg * (CDIM / 64);       // 12 c's per thread

    const float4* spv  = (const float4*)(sp  + (size_t)b * CDIM * SDIM + s0) + (size_t)c0 * SV + si;
    nfloat4*      outv = (nfloat4*)     (out + (size_t)b * CDIM * SDIM + s0) + (size_t)c0 * SV + si;

    float4 x[12];
    float sx = 0, sy = 0, sz = 0, sw = 0;
    float qx = 0, qy = 0, qz = 0, qw = 0;
#pragma unroll
    for (int j = 0; j < 12; ++j) {
        float4 v = spv[(size_t)j * SV];
        float  p = s_proj[c0 + j];
        v.x += p; v.y += p; v.z += p; v.w += p;
        x[j] = v;
        sx += v.x; sy += v.y; sz += v.z; sw += v.w;
        qx += v.x * v.x; qy += v.y * v.y; qz += v.z * v.z; qw += v.w * v.w;
    }
    red_s[cg][si] = make_float4(sx, sy, sz, sw);
    red_q[cg][si] = make_float4(qx, qy, qz, qw);
    __syncthreads();

    // stage 1: 64 partials per si -> 8 partials per si
    if (t < 64) {
        const int si2 = t & 7;
        const int h   = t >> 3;
        float4 S = make_float4(0, 0, 0, 0), Q = make_float4(0, 0, 0, 0);
#pragma unroll
        for (int g = h * 8; g < h * 8 + 8; ++g) {
            float4 a = red_s[g][si2], q = red_q[g][si2];
            S.x += a.x; S.y += a.y; S.z += a.z; S.w += a.w;
            Q.x += q.x; Q.y += q.y; Q.z += q.z; Q.w += q.w;
        }
        red2_s[h][si2] = S;
        red2_q[h][si2] = Q;
    }
    __syncthreads();

    // stage 2: final 8 -> mu/rs per s-column
    if (t < 8) {
        float4 S = make_float4(0, 0, 0, 0), Q = make_float4(0, 0, 0, 0);
#pragma unroll
        for (int h = 0; h < 8; ++h) {
            float4 a = red2_s[h][t], q = red2_q[h][t];
            S.x += a.x; S.y += a.y; S.z += a.z; S.w += a.w;
            Q.x += q.x; Q.y += q.y; Q.z += q.z; Q.w += q.w;
        }
        const float inv = 1.f / CDIM;
        float4 mu = make_float4(S.x * inv, S.y * inv, S.z * inv, S.w * inv);
        float4 rs;
        rs.x = rsqrtf(Q.x * inv - mu.x * mu.x + 1e-5f);
        rs.y = rsqrtf(Q.y * inv - mu.y * mu.y + 1e-5f);
        rs.z = rsqrtf(Q.z * inv - mu.z * mu.z + 1e-5f);
        rs.w = rsqrtf(Q.w * inv - mu.w * mu.w + 1e-5f);
        s_mu[t] = mu;
        s_rs[t] = rs;
    }
    __syncthreads();

    const float4 mu = s_mu[si];
    const float4 rs = s_rs[si];
#pragma unroll
    for (int j = 0; j < 12; ++j) {
        float g  = s_gamma[c0 + j];
        float be = s_beta[c0 + j];
        nfloat4 y;
        y.x = (x[j].x - mu.x) * rs.x * g + be;
        y.y = (x[j].y - mu.y) * rs.y * g + be;
        y.z = (x[j].z - mu.z) * rs.z * g + be;
        y.w = (x[j].w - mu.w) * rs.w * g + be;
        __builtin_nontemporal_store(y, &outv[(size_t)j * SV]);
    }
}

extern "C" void kernel_launch(void* const* d_in, const int* in_sizes, int n_in,
                              void* d_out, int out_size, void* d_ws, size_t ws_size,
                              hipStream_t stream) {
    const float* sp           = (const float*)d_in[0];
    const float* conditioning = (const float*)d_in[1];
    const float* w_cond       = (const float*)d_in[2];
    const float* b_cond       = (const float*)d_in[3];
    const float* in_proj_w    = (const float*)d_in[4];
    const float* in_proj_b    = (const float*)d_in[5];
    const float* attn_out_w   = (const float*)d_in[6];
    const float* attn_out_b   = (const float*)d_in[7];
    const float* w_out        = (const float*)d_in[8];
    const float* b_out        = (const float*)d_in[9];
    const float* ln_gamma     = (const float*)d_in[10];
    const float* ln_beta      = (const float*)d_in[11];
    float* out = (float*)d_out;
    float* ws  = (float*)d_ws;

    float* cond = ws;            // 16*768
    float* v    = ws + 12288;    // 16*768
    float* attn = ws + 24576;    // 16*768
    float* proj = ws + 36864;    // 16*768

    const int gemm_blocks = (16 * CDIM) / 4; // 4 waves/block, one wave per output
    small_gemm_kernel<<<gemm_blocks, 256, 0, stream>>>(
        conditioning, w_cond, b_cond, cond, CDIM, 1024);
    small_gemm_kernel<<<gemm_blocks, 256, 0, stream>>>(
        cond, in_proj_w + 2 * CDIM * CDIM, in_proj_b + 2 * CDIM, v, CDIM, CDIM);
    small_gemm_kernel<<<gemm_blocks, 256, 0, stream>>>(
        v, attn_out_w, attn_out_b, attn, CDIM, CDIM);
    small_gemm_kernel<<<gemm_blocks, 256, 0, stream>>>(
        attn, w_out, b_out, proj, CDIM, CDIM);

    dim3 grid(SDIM / 32, 16);
    fused_add_ln_1pass<<<grid, 512, 0, stream>>>(sp, proj, ln_gamma, ln_beta, out);
}